// Round 4
// baseline (236.594 us; speedup 1.0000x reference)
//
#include <hip/hip_runtime.h>
#include <math.h>

// Problem constants
#define NB 128     // batch
#define NC 128     // channels
#define NN 170     // nodes
#define NT 12      // length
#define NP 192     // padded node count (12 tiles of 16) for xst/Ed
#define MP 176     // P row stride (halfs)
#define MEST 192   // Est padded rows

// Workspace regions (halfs)
#define EST_SZ ((size_t)MEST * NC)          //    24,576 halfs (48 KB)
#define XST_SZ ((size_t)NB * NP * NC)       // 3,145,728 halfs (6.3 MB)
#define ED_SZ  ((size_t)NB * NP * NP)       // 4,718,592 halfs (9.4 MB)
#define P_SZ   ((size_t)NB * NN * MP)       // 3,829,760 halfs (7.3 MB)

typedef _Float16 h8 __attribute__((ext_vector_type(8)));
typedef float    f4 __attribute__((ext_vector_type(4)));

// tanh via hw exp+rcp. NOTE the clamp also sanitizes NaN/Inf (fmaxf(NaN,-15)
// = -15 per IEEE) — reads of unwritten (poisoned) xst pad rows produce
// finite garbage that only feeds discarded score-columns.
__device__ __forceinline__ float fast_tanh(float x) {
    float cx = fminf(fmaxf(x, -15.f), 15.f);
    float e  = __expf(2.f * cx);
    return (e - 1.f) * __builtin_amdgcn_rcpf(e + 1.f);
}

// ---------------------------------------------------------------------------
// K1: blocks [0,2048): (b, c-octet) -> xst[b][n][c0..c0+7] = f16(sum_t x).
//   Reads 8 channel-rows = 65.3 KB *contiguous* (lane-consecutive float4 —
//   the R2/R3 version read 96B-per-lane gathers, ~96 cache lines per
//   instruction, which pinned it at ~2.5 TB/s). Per-float4 sums go to LDS
//   (write: consecutive banks; read: 3-stride, gcd(3,32)=1 => conflict-free),
//   then thread n emits one h8 (16B) transposed store.
// blocks [2048,2144): Est[m][c] = f16(Es[c][m]), rows m in [170,192) zeroed
//   (these zeros also make Ed cols >=170 exact zeros downstream).
// xst pad rows n in [170,192) left unwritten — see fast_tanh note.
// ---------------------------------------------------------------------------
__global__ __launch_bounds__(256) void k1_tsum_est(const float* __restrict__ x,
                                                   const float* __restrict__ Es,
                                                   _Float16* __restrict__ xst,
                                                   _Float16* __restrict__ Est) {
    const int bid = blockIdx.x;
    const int t = threadIdx.x;
    if (bid < 2048) {
        const int b = bid >> 4, c0 = (bid & 15) * 8;
        __shared__ float L[8][512];                 // 16 KB
        const float4* xq = reinterpret_cast<const float4*>(
            x + ((size_t)(b * NC + c0)) * (NN * NT));   // 8 rows, 4080 float4
        #pragma unroll
        for (int it = 0; it < 16; ++it) {
            int s = t + it * 256;                   // [0,4096)
            if (s < 4080) {
                float4 v = xq[s];
                int c = s / 510, r = s - c * 510;
                L[c][r] = (v.x + v.y) + (v.z + v.w);
            }
        }
        __syncthreads();
        if (t < NN) {
            h8 o;
            #pragma unroll
            for (int c = 0; c < 8; ++c)
                o[c] = (_Float16)(L[c][3 * t] + L[c][3 * t + 1] + L[c][3 * t + 2]);
            *reinterpret_cast<h8*>(xst + ((size_t)b * NP + t) * NC + c0) = o;
        }
    } else {
        int idx = (bid - 2048) * 256 + t;           // [0, 192*128)
        int m = idx >> 7, c = idx & 127;
        Est[idx] = (m < NN) ? (_Float16)Es[c * NN + m] : (_Float16)0.f;
    }
}

// ---------------------------------------------------------------------------
// K2: Ed[b][n][m] = tanh( sum_c xst[b][n][c] * Est[m][c] ), stride-192 rows.
// ZERO LDS, ZERO barriers: A- and B-fragments are contiguous h8 loads
// straight from L2 (xst 6.3 MB, Est 48 KB). Grid (6,128) = 3 blocks/CU,
// 12 waves/CU of pure independent-load + MFMA work — latency hidden by TLP
// instead of exposed by __syncthreads (the R1-R3 lesson).
// MFMA pattern is the HW-verified A*B^T family (D: col=lane&15, row=quad*4+reg).
// All 192 n-rows and 192 m-cols written: m in [170,192) = tanh(0) = 0 exactly
// (Est pad rows zero); n in [170,192) = finite garbage, consumed only by
// discarded score-columns in K3.
// ---------------------------------------------------------------------------
__global__ __launch_bounds__(256) void k2_ed_mfma(const _Float16* __restrict__ xst,
                                                  const _Float16* __restrict__ Est,
                                                  _Float16* __restrict__ Ed) {
    const int b = blockIdx.y, n0 = blockIdx.x * 32;
    const int t = threadIdx.x;
    const int lane = t & 63, wave = t >> 6;
    const int l15 = lane & 15, quad = lane >> 4;

    const _Float16* __restrict__ xb = xst + (size_t)b * NP * NC;

    f4 acc[2][3] = {};
    #pragma unroll
    for (int kk = 0; kk < 4; ++kk) {                // K = 128, chunks of 32
        int ks = kk * 32 + quad * 8;
        h8 a0 = *reinterpret_cast<const h8*>(xb + (size_t)(n0 + l15) * NC + ks);
        h8 a1 = *reinterpret_cast<const h8*>(xb + (size_t)(n0 + 16 + l15) * NC + ks);
        #pragma unroll
        for (int ci = 0; ci < 3; ++ci) {
            int m = (wave * 3 + ci) * 16 + l15;
            h8 bf = *reinterpret_cast<const h8*>(Est + (size_t)m * NC + ks);
            acc[0][ci] = __builtin_amdgcn_mfma_f32_16x16x32_f16(a0, bf, acc[0][ci], 0, 0, 0);
            acc[1][ci] = __builtin_amdgcn_mfma_f32_16x16x32_f16(a1, bf, acc[1][ci], 0, 0, 0);
        }
    }
    #pragma unroll
    for (int rt = 0; rt < 2; ++rt)
        #pragma unroll
        for (int ci = 0; ci < 3; ++ci) {
            int m = (wave * 3 + ci) * 16 + l15;
            #pragma unroll
            for (int reg = 0; reg < 4; ++reg) {
                int n = n0 + rt * 16 + quad * 4 + reg;
                Ed[((size_t)b * NP + n) * NP + m] = (_Float16)fast_tanh(acc[rt][ci][reg]);
            }
        }
}

// ---------------------------------------------------------------------------
// K3: scores = relu(Ed[b]·Ed[b]^T / sqrt(C)), row softmax -> P (f16).
// GEMM side is LDS-free / barrier-free: per 32-wide K-chunk each wave issues
// 5 independent contiguous h8 loads from L2 (2 A-frags for this block's 32
// rows, 3 B-frags covering its 48 score-cols) + 6 MFMA. K runs over all 192
// cols of Ed — cols >=170 are exact zeros, so the sum is unchanged.
// LDS only for the proven Sc scatter + wave-parallel softmax (one barrier
// pair total, vs 12 in the R1/R2 chunk-staged version).
// ---------------------------------------------------------------------------
#define SCSTR 204

__global__ __launch_bounds__(256) void k3_scores_mfma(const _Float16* __restrict__ Ed,
                                                      _Float16* __restrict__ P) {
    const int b = blockIdx.y, r0 = blockIdx.x * 32;
    const int t = threadIdx.x;
    const int lane = t & 63, wave = t >> 6;
    const int l15 = lane & 15, quad = lane >> 4;

    __shared__ __align__(16) float Sc[32 * SCSTR];  // 26.1 KB

    const _Float16* __restrict__ Eb = Ed + (size_t)b * NP * NP;

    f4 acc[2][3] = {};
    #pragma unroll 2
    for (int mc = 0; mc < 192; mc += 32) {
        int ks = mc + quad * 8;
        h8 a0 = *reinterpret_cast<const h8*>(Eb + (size_t)(r0 + l15) * NP + ks);
        h8 a1 = *reinterpret_cast<const h8*>(Eb + (size_t)(r0 + 16 + l15) * NP + ks);
        #pragma unroll
        for (int ci = 0; ci < 3; ++ci) {
            int kc = (wave * 3 + ci) * 16 + l15;    // B row (= score col)
            h8 bf = *reinterpret_cast<const h8*>(Eb + (size_t)kc * NP + ks);
            acc[0][ci] = __builtin_amdgcn_mfma_f32_16x16x32_f16(a0, bf, acc[0][ci], 0, 0, 0);
            acc[1][ci] = __builtin_amdgcn_mfma_f32_16x16x32_f16(a1, bf, acc[1][ci], 0, 0, 0);
        }
    }

    // Scatter scaled+relu scores to Sc.
    const float scale = 0.08838834764831845f;       // 1/sqrt(128)
    #pragma unroll
    for (int rt = 0; rt < 2; ++rt)
        #pragma unroll
        for (int ci = 0; ci < 3; ++ci) {
            int col = (wave * 3 + ci) * 16 + l15;
            #pragma unroll
            for (int reg = 0; reg < 4; ++reg) {
                int rloc = rt * 16 + quad * 4 + reg;
                Sc[rloc * SCSTR + col] = fmaxf(acc[rt][ci][reg] * scale, 0.f);
            }
        }
    __syncthreads();

    // Softmax: wave w owns rows w*8 .. w*8+7 (proven R1 pattern).
    for (int rr = 0; rr < 8; ++rr) {
        int r = wave * 8 + rr;
        int n = r0 + r;
        if (n >= NN) continue;                      // wave-uniform
        float v0 = Sc[r * SCSTR + lane];
        float v1 = Sc[r * SCSTR + lane + 64];
        int  k2i = lane + 128;
        bool has2 = (k2i < NN);
        float v2 = has2 ? Sc[r * SCSTR + k2i] : -1.f;
        float m = fmaxf(fmaxf(v0, v1), v2);
        #pragma unroll
        for (int off = 32; off; off >>= 1) m = fmaxf(m, __shfl_xor(m, off, 64));
        float e0 = __expf(v0 - m);
        float e1 = __expf(v1 - m);
        float e2 = has2 ? __expf(v2 - m) : 0.f;
        float s = e0 + e1 + e2;
        #pragma unroll
        for (int off = 32; off; off >>= 1) s += __shfl_xor(s, off, 64);
        float inv = 1.f / s;
        _Float16* Pr = P + ((size_t)(b * NN + n)) * MP;
        Pr[lane]      = (_Float16)(e0 * inv);
        Pr[lane + 64] = (_Float16)(e1 * inv);
        if (has2) Pr[k2i] = (_Float16)(e2 * inv);
    }
}

// ---------------------------------------------------------------------------
// K4: mean over batch + threshold in one pass (unchanged, proven).
// ---------------------------------------------------------------------------
__global__ __launch_bounds__(256) void k4_mean_thresh(const _Float16* __restrict__ P,
                                                      float* __restrict__ out) {
    int p = blockIdx.x * 256 + threadIdx.x;
    if (p >= NN * NN) return;
    int n = p / NN, k = p - n * NN;
    const _Float16* base = P + (size_t)n * MP + k;
    float s0 = 0.f, s1 = 0.f, s2 = 0.f, s3 = 0.f;
    #pragma unroll
    for (int b = 0; b < NB; b += 4) {
        s0 += (float)base[(size_t)(b + 0) * NN * MP];
        s1 += (float)base[(size_t)(b + 1) * NN * MP];
        s2 += (float)base[(size_t)(b + 2) * NN * MP];
        s3 += (float)base[(size_t)(b + 3) * NN * MP];
    }
    float s = (s0 + s1) + (s2 + s3);
    out[p] = (s * (1.f / 128.f) > 0.5f) ? 1.f : 0.f;
}

// ---------------------------------------------------------------------------
// Workspace layout (halfs):
//   [0, EST_SZ)   : Est (f16, [192][128])     live through K2
//   [+, +XST_SZ)  : xst (f16, [b][192n][128c]) dead after K2
//   [+, +ED_SZ)   : Ed  (f16, [b][192][192])  dead after K3
//   [+, +P_SZ)    : P   (f16, [b][n][176])    dead after K4
// Total = 23.2 MB.
// ---------------------------------------------------------------------------
extern "C" void kernel_launch(void* const* d_in, const int* in_sizes, int n_in,
                              void* d_out, int out_size, void* d_ws, size_t ws_size,
                              hipStream_t stream) {
    const float* x  = (const float*)d_in[0];   // [128,128,170,12] f32
    const float* Es = (const float*)d_in[1];   // [128,170] f32
    float* out = (float*)d_out;                // [170,170] f32

    _Float16* Est = (_Float16*)d_ws;
    _Float16* xst = Est + EST_SZ;
    _Float16* Ed  = xst + XST_SZ;
    _Float16* P   = Ed + ED_SZ;

    k1_tsum_est<<<2144, 256, 0, stream>>>(x, Es, xst, Est);
    k2_ed_mfma<<<dim3(6, 128), 256, 0, stream>>>(xst, Est, Ed);
    k3_scores_mfma<<<dim3(6, 128), 256, 0, stream>>>(Ed, P);
    k4_mean_thresh<<<113, 256, 0, stream>>>(P, out);
}

// Round 5
// 220.506 us; speedup vs baseline: 1.0730x; 1.0730x over previous
//
#include <hip/hip_runtime.h>
#include <math.h>

// Problem constants
#define NB 128     // batch
#define NC 128     // channels
#define NN 170     // nodes
#define NT 12     // length
#define NP 192     // padded node count (12 tiles of 16)
#define MP 176     // P row stride (halfs)

// Workspace regions (halfs)
#define EST_SZ ((size_t)NP * NC)            //   24,576 halfs (48 KB)
#define P_SZ   ((size_t)NB * NN * MP)       // 3,829,760 halfs (7.3 MB)

typedef _Float16 h8 __attribute__((ext_vector_type(8)));
typedef float    f4 __attribute__((ext_vector_type(4)));

// tanh via hw exp+rcp: ~6 VALU ops. rel err ~1e-6. Clamp sanitizes inf.
__device__ __forceinline__ float fast_tanh(float x) {
    float cx = fminf(fmaxf(x, -15.f), 15.f);
    float e  = __expf(2.f * cx);
    return (e - 1.f) * __builtin_amdgcn_rcpf(e + 1.f);
}

// ---------------------------------------------------------------------------
// KPREP: Est[m][c] = f16(Es[c][m]) for m<170, rows [170,192) zero (these
// zeros make Ed's pad cols exact zeros downstream). Proven (R4 tail blocks).
// ---------------------------------------------------------------------------
__global__ __launch_bounds__(256) void kprep_est(const float* __restrict__ Es,
                                                 _Float16* __restrict__ Est) {
    int idx = blockIdx.x * 256 + threadIdx.x;       // [0, 192*128)
    int m = idx >> 7, c = idx & 127;
    Est[idx] = (m < NN) ? (_Float16)Es[c * NN + m] : (_Float16)0.f;
}

// ---------------------------------------------------------------------------
// KA (one block per batch, 1024 threads = 16 waves = 4/SIMD):
//   phase1: x[b] (1.04 MB coalesced) -> t-sum via LDS (8 rounds x 16 ch)
//           -> At = xs^T f16 swizzled in LDS (rows >=170 exact zero)
//   GEMM1:  EdL[n][m] = tanh(sum_c At[n][c] * Est[m][c])  (LDS only;
//           pad rows AND cols exact 0 since At pad rows / Est pad rows are 0)
//   GEMM2:  acc2 = EdL · EdL^T  (wave (wr,wc) owns 48x48 output tile)
//   4 rounds: scatter 48 rows -> Sc (aliases At) -> proven wave softmax -> P.
// All MFMA/swizzle patterns are the HW-verified R3/R4 family:
//   A*B^T, both operands k-contiguous h8 at quad*8; D: col=lane&15,
//   row=quad*4+reg; XOR swizzle on 16B groups: group' = group ^ (row&7).
// LDS: 32,640 (L) + 49,152 (At/Sc) + 73,728 (EdL) = 155,520 B -> 1 block/CU.
// Why 16 waves: R3's mega-fusion ran 4 waves = 1/SIMD (zero latency hiding,
// neutral result). This is the same fusion with 4x the TLP and a coalesced
// x-read, 8 float4 in flight per thread.
// ---------------------------------------------------------------------------
#define ATSW(row, c)  ((row) * 128 + (((((c) >> 3) ^ ((row) & 7)) << 3) | ((c) & 7)))
#define EDSW(row, m)  ((row) * 192 + (((((m) >> 3) ^ ((row) & 7)) << 3) | ((m) & 7)))
#define SCSTR 204

__global__ __launch_bounds__(1024) void kA_fused(const float* __restrict__ x,
                                                 const _Float16* __restrict__ Est,
                                                 _Float16* __restrict__ P) {
    const int b = blockIdx.x;
    const int t = threadIdx.x;                      // [0,1024)
    const int lane = t & 63, wave = t >> 6;         // wave [0,16)
    const int l15 = lane & 15, quad = lane >> 4;
    const int wr = wave >> 2, wc = wave & 3;        // 4x4 wave grid

    __shared__ __align__(16) float    L[16 * 510];       // 32,640 B t-sum partials
    __shared__ __align__(16) char     UN[192 * 128 * 2]; // 49,152 B At, later Sc
    __shared__ __align__(16) _Float16 EdL[192 * 192];    // 73,728 B
    _Float16* At = (_Float16*)UN;                   // [192 n][128 c] swizzled
    float*    Sc = (float*)UN;                      // [48][SCSTR] f32 (39,168 B)

    // ---- phase 1: t-sum. Each round: 16 channels = 8160 float4 coalesced ----
    const float4* xb = reinterpret_cast<const float4*>(x + (size_t)b * NC * NN * NT);
    for (int r8 = 0; r8 < 8; ++r8) {
        float4 vv[8];
        #pragma unroll
        for (int it = 0; it < 8; ++it) {            // issue all 8 loads first
            int s = t + it * 1024;
            vv[it] = (s < 8160) ? xb[(size_t)r8 * 8160 + s]
                                : make_float4(0.f, 0.f, 0.f, 0.f);
        }
        #pragma unroll
        for (int it = 0; it < 8; ++it) {
            int s = t + it * 1024;
            if (s < 8160)
                L[s] = (vv[it].x + vv[it].y) + (vv[it].z + vv[it].w);
        }
        __syncthreads();
        // reduce 3:1 -> At. idx: n-major so LDS reads stride 510 (bank-clean)
        #pragma unroll
        for (int it = 0; it < 3; ++it) {
            int idx = t + it * 1024;                // [0, 3072) = 192n x 16c
            int n = idx >> 4, cc = idx & 15;
            float s = 0.f;
            if (n < NN)
                s = L[cc * 510 + 3 * n] + L[cc * 510 + 3 * n + 1]
                  + L[cc * 510 + 3 * n + 2];
            At[ATSW(n, r8 * 16 + cc)] = (_Float16)s; // n>=170 rows exact 0
        }
        __syncthreads();
    }

    // ---- GEMM1: EdL = tanh(At · Est^T), wave tile 48 rows x 48 cols ----
    {
        f4 acc1[3][3] = {};
        #pragma unroll
        for (int kk = 0; kk < 4; ++kk) {            // K = 128
            int ks = kk * 32 + quad * 8;
            h8 a[3], bf[3];
            #pragma unroll
            for (int rt = 0; rt < 3; ++rt) {
                int row = wr * 48 + rt * 16 + l15;
                a[rt] = *reinterpret_cast<const h8*>(
                    &At[row * 128 + (((ks >> 3) ^ (row & 7)) << 3)]);
            }
            #pragma unroll
            for (int ci = 0; ci < 3; ++ci) {
                int m = wc * 48 + ci * 16 + l15;
                bf[ci] = *reinterpret_cast<const h8*>(Est + (size_t)m * NC + ks);
            }
            #pragma unroll
            for (int rt = 0; rt < 3; ++rt)
                #pragma unroll
                for (int ci = 0; ci < 3; ++ci)
                    acc1[rt][ci] = __builtin_amdgcn_mfma_f32_16x16x32_f16(
                        a[rt], bf[ci], acc1[rt][ci], 0, 0, 0);
        }
        // epilogue: tanh -> EdL (swizzled b16 writes)
        #pragma unroll
        for (int rt = 0; rt < 3; ++rt)
            #pragma unroll
            for (int ci = 0; ci < 3; ++ci) {
                int m = wc * 48 + ci * 16 + l15;
                #pragma unroll
                for (int reg = 0; reg < 4; ++reg) {
                    int n = wr * 48 + rt * 16 + quad * 4 + reg;
                    EdL[EDSW(n, m)] = (_Float16)fast_tanh(acc1[rt][ci][reg]);
                }
            }
    }
    __syncthreads();                                // EdL complete

    // ---- GEMM2: acc2 = EdL · EdL^T, wave (wr,wc) -> rows wr*48, cols wc*48 ----
    f4 acc2[3][3] = {};
    #pragma unroll 2
    for (int mc = 0; mc < 192; mc += 32) {          // K = 192 (pad cols are 0)
        int mg = (mc >> 3) + quad;
        h8 a2[3], b2[3];
        #pragma unroll
        for (int rt = 0; rt < 3; ++rt) {
            int row = wr * 48 + rt * 16 + l15;
            a2[rt] = *reinterpret_cast<const h8*>(
                &EdL[row * 192 + ((mg ^ (row & 7)) << 3)]);
        }
        #pragma unroll
        for (int ci = 0; ci < 3; ++ci) {
            int row = wc * 48 + ci * 16 + l15;      // score col base
            b2[ci] = *reinterpret_cast<const h8*>(
                &EdL[row * 192 + ((mg ^ (row & 7)) << 3)]);
        }
        #pragma unroll
        for (int rt = 0; rt < 3; ++rt)
            #pragma unroll
            for (int ci = 0; ci < 3; ++ci)
                acc2[rt][ci] = __builtin_amdgcn_mfma_f32_16x16x32_f16(
                    a2[rt], b2[ci], acc2[rt][ci], 0, 0, 0);
    }

    // ---- 4 rounds of 48 rows: scatter (waves wr==p) -> softmax (all) ----
    const float scale = 0.08838834764831845f;       // 1/sqrt(128)
    for (int p = 0; p < 4; ++p) {
        __syncthreads();                            // prev round's Sc reads done
        if (wr == p) {
            #pragma unroll
            for (int rt = 0; rt < 3; ++rt)
                #pragma unroll
                for (int ci = 0; ci < 3; ++ci) {
                    int col = wc * 48 + ci * 16 + l15;
                    #pragma unroll
                    for (int reg = 0; reg < 4; ++reg) {
                        int rloc = rt * 16 + quad * 4 + reg;
                        Sc[rloc * SCSTR + col] = fmaxf(acc2[rt][ci][reg] * scale, 0.f);
                    }
                }
        }
        __syncthreads();
        // proven wave-parallel softmax; wave owns 3 rows of this 48-row round
        #pragma unroll
        for (int rr = 0; rr < 3; ++rr) {
            int r = wave * 3 + rr;
            int n = p * 48 + r;
            if (n >= NN) continue;
            float v0 = Sc[r * SCSTR + lane];
            float v1 = Sc[r * SCSTR + lane + 64];
            int  k2i = lane + 128;
            bool has2 = (k2i < NN);
            float v2 = has2 ? Sc[r * SCSTR + k2i] : -1.f;
            float m = fmaxf(fmaxf(v0, v1), v2);
            #pragma unroll
            for (int off = 32; off; off >>= 1) m = fmaxf(m, __shfl_xor(m, off, 64));
            float e0 = __expf(v0 - m);
            float e1 = __expf(v1 - m);
            float e2 = has2 ? __expf(v2 - m) : 0.f;
            float s = e0 + e1 + e2;
            #pragma unroll
            for (int off = 32; off; off >>= 1) s += __shfl_xor(s, off, 64);
            float inv = 1.f / s;
            _Float16* Pr = P + ((size_t)(b * NN + n)) * MP;
            Pr[lane]      = (_Float16)(e0 * inv);
            Pr[lane + 64] = (_Float16)(e1 * inv);
            if (has2) Pr[k2i] = (_Float16)(e2 * inv);
        }
    }
}

// ---------------------------------------------------------------------------
// K4: mean over batch + threshold in one pass (unchanged, proven).
// ---------------------------------------------------------------------------
__global__ __launch_bounds__(256) void k4_mean_thresh(const _Float16* __restrict__ P,
                                                      float* __restrict__ out) {
    int p = blockIdx.x * 256 + threadIdx.x;
    if (p >= NN * NN) return;
    int n = p / NN, k = p - n * NN;
    const _Float16* base = P + (size_t)n * MP + k;
    float s0 = 0.f, s1 = 0.f, s2 = 0.f, s3 = 0.f;
    #pragma unroll
    for (int b = 0; b < NB; b += 4) {
        s0 += (float)base[(size_t)(b + 0) * NN * MP];
        s1 += (float)base[(size_t)(b + 1) * NN * MP];
        s2 += (float)base[(size_t)(b + 2) * NN * MP];
        s3 += (float)base[(size_t)(b + 3) * NN * MP];
    }
    float s = (s0 + s1) + (s2 + s3);
    out[p] = (s * (1.f / 128.f) > 0.5f) ? 1.f : 0.f;
}

// ---------------------------------------------------------------------------
// Workspace layout (halfs):
//   [0, EST_SZ)   : Est (f16, [192][128])   live through KA
//   [+, +P_SZ)    : P   (f16, [b][n][176])  dead after K4
// Total = 7.4 MB (xs/Ed now LDS-resident; no other intermediates).
// ---------------------------------------------------------------------------
extern "C" void kernel_launch(void* const* d_in, const int* in_sizes, int n_in,
                              void* d_out, int out_size, void* d_ws, size_t ws_size,
                              hipStream_t stream) {
    const float* x  = (const float*)d_in[0];   // [128,128,170,12] f32
    const float* Es = (const float*)d_in[1];   // [128,170] f32
    float* out = (float*)d_out;                // [170,170] f32

    _Float16* Est = (_Float16*)d_ws;
    _Float16* P   = Est + EST_SZ;

    kprep_est<<<96, 256, 0, stream>>>(Es, Est);
    kA_fused<<<128, 1024, 0, stream>>>(x, Est, P);
    k4_mean_thresh<<<113, 256, 0, stream>>>(P, out);
}

// Round 7
// 219.527 us; speedup vs baseline: 1.0777x; 1.0045x over previous
//
#include <hip/hip_runtime.h>
#include <math.h>

// Problem constants
#define NB 128     // batch
#define NC 128     // channels
#define NN 170     // nodes
#define NT 12      // length
#define NP 192     // padded node count (12 tiles of 16)
#define MP 176     // P row stride (halfs)

// Workspace regions (halfs)
#define EST_SZ ((size_t)NP * NC)            //   24,576 halfs (48 KB)
#define P_SZ   ((size_t)NB * NN * MP)       // 3,829,760 halfs (7.3 MB)

typedef _Float16 h8 __attribute__((ext_vector_type(8)));
typedef float    f4 __attribute__((ext_vector_type(4)));

// tanh via hw exp+rcp: ~6 VALU ops. rel err ~1e-6. Clamp sanitizes inf.
__device__ __forceinline__ float fast_tanh(float x) {
    float cx = fminf(fmaxf(x, -15.f), 15.f);
    float e  = __expf(2.f * cx);
    return (e - 1.f) * __builtin_amdgcn_rcpf(e + 1.f);
}

// ---------------------------------------------------------------------------
// KPREP: Est[m][c] = f16(Es[c][m]) for m<170, rows [170,192) zero (these
// zeros make EdL's pad cols exact zeros downstream). Proven.
// ---------------------------------------------------------------------------
__global__ __launch_bounds__(256) void kprep_est(const float* __restrict__ Es,
                                                 _Float16* __restrict__ Est) {
    int idx = blockIdx.x * 256 + threadIdx.x;       // [0, 192*128)
    int m = idx >> 7, c = idx & 127;
    Est[idx] = (m < NN) ? (_Float16)Es[c * NN + m] : (_Float16)0.f;
}

// ---------------------------------------------------------------------------
// KA — grid (2,128): block (h, b) = half h of batch b. 1024 thr = 16 waves.
// R5 measured the 128-block version at 78.6us with HALF THE CHIP IDLE
// (MfmaUtil 1.4%, VALUBusy 8.9%: pure latency-bound). This version is the
// same proven code at 256 blocks = 1 block/CU on ALL 256 CUs:
//   phase1 + GEMM1 (full EdL) duplicated per half — x re-read is mostly
//   L3-absorbed (R5 FETCH showed L3 already supplies half of x), GEMM1 dup
//   costs ~1us aggregate; GEMM2/softmax/P-write cover only rows [h*96,h*96+96).
// All MFMA/swizzle patterns are the HW-verified family: A*B^T, operands
// k-contiguous h8 at quad*8; D: col=lane&15, row=quad*4+reg; XOR swizzle
// group' = group ^ (row&7) on 16B groups.
// LDS: 32,640 (L) + 49,152 (At/Sc) + 73,728 (EdL) = 155,520 B -> 1 block/CU.
// (R6 bench attempt was an infra double-failure — resubmitted unchanged.)
// ---------------------------------------------------------------------------
#define ATSW(row, c)  ((row) * 128 + (((((c) >> 3) ^ ((row) & 7)) << 3) | ((c) & 7)))
#define EDSW(row, m)  ((row) * 192 + (((((m) >> 3) ^ ((row) & 7)) << 3) | ((m) & 7)))
#define SCSTR 204

__global__ __launch_bounds__(1024) void kA_fused(const float* __restrict__ x,
                                                 const _Float16* __restrict__ Est,
                                                 _Float16* __restrict__ P) {
    const int h = blockIdx.x, b = blockIdx.y;
    const int r0 = h * 96;                          // this block's output rows
    const int t = threadIdx.x;                      // [0,1024)
    const int lane = t & 63, wave = t >> 6;         // wave [0,16)
    const int l15 = lane & 15, quad = lane >> 4;
    const int wr = wave >> 2, wc = wave & 3;        // 4x4 wave grid (GEMM1)

    __shared__ __align__(16) float    L[16 * 510];       // 32,640 B t-sum partials
    __shared__ __align__(16) char     UN[192 * 128 * 2]; // 49,152 B At, later Sc
    __shared__ __align__(16) _Float16 EdL[192 * 192];    // 73,728 B
    _Float16* At = (_Float16*)UN;                   // [192 n][128 c] swizzled
    float*    Sc = (float*)UN;                      // [48][SCSTR] f32 (39,168 B)

    // ---- phase 1: t-sum. Each round: 16 channels = 8160 float4 coalesced ----
    const float4* xb = reinterpret_cast<const float4*>(x + (size_t)b * NC * NN * NT);
    for (int r8 = 0; r8 < 8; ++r8) {
        float4 vv[8];
        #pragma unroll
        for (int it = 0; it < 8; ++it) {            // issue all 8 loads first
            int s = t + it * 1024;
            vv[it] = (s < 8160) ? xb[(size_t)r8 * 8160 + s]
                                : make_float4(0.f, 0.f, 0.f, 0.f);
        }
        #pragma unroll
        for (int it = 0; it < 8; ++it) {
            int s = t + it * 1024;
            if (s < 8160)
                L[s] = (vv[it].x + vv[it].y) + (vv[it].z + vv[it].w);
        }
        __syncthreads();
        // reduce 3:1 -> At. n-major so LDS reads stride 510 (bank-clean)
        #pragma unroll
        for (int it = 0; it < 3; ++it) {
            int idx = t + it * 1024;                // [0, 3072) = 192n x 16c
            int n = idx >> 4, cc = idx & 15;
            float s = 0.f;
            if (n < NN)
                s = L[cc * 510 + 3 * n] + L[cc * 510 + 3 * n + 1]
                  + L[cc * 510 + 3 * n + 2];
            At[ATSW(n, r8 * 16 + cc)] = (_Float16)s; // n>=170 rows exact 0
        }
        __syncthreads();
    }

    // ---- GEMM1: EdL = tanh(At · Est^T), 16 waves, tile 48x48 each ----
    {
        f4 acc1[3][3] = {};
        #pragma unroll
        for (int kk = 0; kk < 4; ++kk) {            // K = 128
            int ks = kk * 32 + quad * 8;
            h8 a[3], bf[3];
            #pragma unroll
            for (int rt = 0; rt < 3; ++rt) {
                int row = wr * 48 + rt * 16 + l15;
                a[rt] = *reinterpret_cast<const h8*>(
                    &At[row * 128 + (((ks >> 3) ^ (row & 7)) << 3)]);
            }
            #pragma unroll
            for (int ci = 0; ci < 3; ++ci) {
                int m = wc * 48 + ci * 16 + l15;
                bf[ci] = *reinterpret_cast<const h8*>(Est + (size_t)m * NC + ks);
            }
            #pragma unroll
            for (int rt = 0; rt < 3; ++rt)
                #pragma unroll
                for (int ci = 0; ci < 3; ++ci)
                    acc1[rt][ci] = __builtin_amdgcn_mfma_f32_16x16x32_f16(
                        a[rt], bf[ci], acc1[rt][ci], 0, 0, 0);
        }
        // epilogue: tanh -> EdL (swizzled b16 writes)
        #pragma unroll
        for (int rt = 0; rt < 3; ++rt)
            #pragma unroll
            for (int ci = 0; ci < 3; ++ci) {
                int m = wc * 48 + ci * 16 + l15;
                #pragma unroll
                for (int reg = 0; reg < 4; ++reg) {
                    int n = wr * 48 + rt * 16 + quad * 4 + reg;
                    EdL[EDSW(n, m)] = (_Float16)fast_tanh(acc1[rt][ci][reg]);
                }
            }
    }
    __syncthreads();                                // EdL complete; At dead

    // ---- GEMM2: this half's 96 rows x 192 cols = 2x4 grid of 48x48 ----
    // Waves 0-7 participate: gr = wave>>2 (row group), gc = wave&3 (col group).
    f4 acc2[3][3] = {};
    if (wave < 8) {
        const int gr = wave >> 2, gc = wave & 3;
        #pragma unroll 2
        for (int mc = 0; mc < 192; mc += 32) {      // K = 192 (pad cols are 0)
            int mg = (mc >> 3) + quad;
            h8 a2[3], b2[3];
            #pragma unroll
            for (int rt = 0; rt < 3; ++rt) {
                int row = r0 + gr * 48 + rt * 16 + l15;
                a2[rt] = *reinterpret_cast<const h8*>(
                    &EdL[row * 192 + ((mg ^ (row & 7)) << 3)]);
            }
            #pragma unroll
            for (int ci = 0; ci < 3; ++ci) {
                int row = gc * 48 + ci * 16 + l15;  // score col base
                b2[ci] = *reinterpret_cast<const h8*>(
                    &EdL[row * 192 + ((mg ^ (row & 7)) << 3)]);
            }
            #pragma unroll
            for (int rt = 0; rt < 3; ++rt)
                #pragma unroll
                for (int ci = 0; ci < 3; ++ci)
                    acc2[rt][ci] = __builtin_amdgcn_mfma_f32_16x16x32_f16(
                        a2[rt], b2[ci], acc2[rt][ci], 0, 0, 0);
        }
    }

    // ---- 2 rounds of 48 rows: scatter (waves gr==p) -> softmax (all) ----
    const float scale = 0.08838834764831845f;       // 1/sqrt(128)
    for (int p = 0; p < 2; ++p) {
        __syncthreads();                            // prev round's Sc reads done
        if (wave < 8 && (wave >> 2) == p) {
            const int gc = wave & 3;
            #pragma unroll
            for (int rt = 0; rt < 3; ++rt)
                #pragma unroll
                for (int ci = 0; ci < 3; ++ci) {
                    int col = gc * 48 + ci * 16 + l15;
                    #pragma unroll
                    for (int reg = 0; reg < 4; ++reg) {
                        int rloc = rt * 16 + quad * 4 + reg;
                        Sc[rloc * SCSTR + col] = fmaxf(acc2[rt][ci][reg] * scale, 0.f);
                    }
                }
        }
        __syncthreads();
        // proven wave-parallel softmax; wave owns 3 rows of this 48-row round
        #pragma unroll
        for (int rr = 0; rr < 3; ++rr) {
            int r = wave * 3 + rr;
            int n = r0 + p * 48 + r;
            if (n >= NN) continue;
            float v0 = Sc[r * SCSTR + lane];
            float v1 = Sc[r * SCSTR + lane + 64];
            int  k2i = lane + 128;
            bool has2 = (k2i < NN);
            float v2 = has2 ? Sc[r * SCSTR + k2i] : -1.f;
            float m = fmaxf(fmaxf(v0, v1), v2);
            #pragma unroll
            for (int off = 32; off; off >>= 1) m = fmaxf(m, __shfl_xor(m, off, 64));
            float e0 = __expf(v0 - m);
            float e1 = __expf(v1 - m);
            float e2 = has2 ? __expf(v2 - m) : 0.f;
            float s = e0 + e1 + e2;
            #pragma unroll
            for (int off = 32; off; off >>= 1) s += __shfl_xor(s, off, 64);
            float inv = 1.f / s;
            _Float16* Pr = P + ((size_t)(b * NN + n)) * MP;
            Pr[lane]      = (_Float16)(e0 * inv);
            Pr[lane + 64] = (_Float16)(e1 * inv);
            if (has2) Pr[k2i] = (_Float16)(e2 * inv);
        }
    }
}

// ---------------------------------------------------------------------------
// K4: mean over batch + threshold in one pass (unchanged, proven).
// ---------------------------------------------------------------------------
__global__ __launch_bounds__(256) void k4_mean_thresh(const _Float16* __restrict__ P,
                                                      float* __restrict__ out) {
    int p = blockIdx.x * 256 + threadIdx.x;
    if (p >= NN * NN) return;
    int n = p / NN, k = p - n * NN;
    const _Float16* base = P + (size_t)n * MP + k;
    float s0 = 0.f, s1 = 0.f, s2 = 0.f, s3 = 0.f;
    #pragma unroll
    for (int b = 0; b < NB; b += 4) {
        s0 += (float)base[(size_t)(b + 0) * NN * MP];
        s1 += (float)base[(size_t)(b + 1) * NN * MP];
        s2 += (float)base[(size_t)(b + 2) * NN * MP];
        s3 += (float)base[(size_t)(b + 3) * NN * MP];
    }
    float s = (s0 + s1) + (s2 + s3);
    out[p] = (s * (1.f / 128.f) > 0.5f) ? 1.f : 0.f;
}

// ---------------------------------------------------------------------------
// Workspace layout (halfs):
//   [0, EST_SZ)   : Est (f16, [192][128])   live through KA
//   [+, +P_SZ)    : P   (f16, [b][n][176])  dead after K4
// Total = 7.4 MB.
// ---------------------------------------------------------------------------
extern "C" void kernel_launch(void* const* d_in, const int* in_sizes, int n_in,
                              void* d_out, int out_size, void* d_ws, size_t ws_size,
                              hipStream_t stream) {
    const float* x  = (const float*)d_in[0];   // [128,128,170,12] f32
    const float* Es = (const float*)d_in[1];   // [128,170] f32
    float* out = (float*)d_out;                // [170,170] f32

    _Float16* Est = (_Float16*)d_ws;
    _Float16* P   = Est + EST_SZ;

    kprep_est<<<96, 256, 0, stream>>>(Es, Est);
    kA_fused<<<dim3(2, 128), 1024, 0, stream>>>(x, Est, P);
    k4_mean_thresh<<<113, 256, 0, stream>>>(P, out);
}